// Round 5
// baseline (861.075 us; speedup 1.0000x reference)
//
#include <hip/hip_runtime.h>
#include <hip/hip_bf16.h>

typedef short bh8 __attribute__((ext_vector_type(8)));
typedef float fx4 __attribute__((ext_vector_type(4)));
typedef int ivec4 __attribute__((ext_vector_type(4)));

typedef __hip_bfloat16 bf16;

__device__ __forceinline__ float bf2f(bf16 v) { return __bfloat162float(v); }
__device__ __forceinline__ bf16 f2bf(float v) { return __float2bfloat16(v); }

// Problem constants
#define BB 8
#define SS 1569
#define CC 768
#define TT 8
#define HWN 196
#define R_T 12544   // B*HW*T
#define R_S 12608   // B*T*197
#define R_H 12552   // B*S

// async global->LDS, 16B per lane; lds dest is wave-uniform base + lane*16
__device__ __forceinline__ void gload16(const void* g, void* l) {
    __builtin_amdgcn_global_load_lds(
        (const __attribute__((address_space(1))) void*)g,
        (__attribute__((address_space(3))) void*)l, 16, 0, 0);
}

// ---------------- transpose + fp32->bf16: out[C][R] = (bf16)in[R][C] ----------------
__global__ __launch_bounds__(256) void k_transpose(const float* __restrict__ in,
                                                   bf16* __restrict__ out,
                                                   int R, int C)
{
    __shared__ float sm[32][33];
    int c0 = blockIdx.x * 32, r0 = blockIdx.y * 32;
    int t = threadIdx.x;
#pragma unroll
    for (int i = 0; i < 4; i++) {
        int e = t + i * 256;
        int r = e >> 5, c = e & 31;
        sm[r][c] = in[(size_t)(r0 + r) * C + (c0 + c)];
    }
    __syncthreads();
#pragma unroll
    for (int i = 0; i < 4; i++) {
        int e = t + i * 256;
        int r = e >> 5, c = e & 31;
        out[(size_t)(c0 + r) * R + (r0 + c)] = f2bf(sm[c][r]);
    }
}

// ---------------- LayerNorm over C=768, one block per row; fp32 in -> bf16 out ----------------
__global__ __launch_bounds__(256) void k_layernorm(
    const float* __restrict__ srcA, const float* __restrict__ srcB,
    const float* __restrict__ gamma, const float* __restrict__ beta,
    bf16* __restrict__ out, int mode)
{
    int r = blockIdx.x;
    const float* row;
    if (mode == 0) {
        int b = r / 1568, rl = r - b * 1568;
        row = srcB + (size_t)(b * SS + 1 + rl) * CC;
    } else if (mode == 1) {
        int seq = r / 197, pos = r - seq * 197;
        int b = seq >> 3, t = seq & 7;
        if (pos == 0) row = srcB + (size_t)(b * SS) * CC;
        else          row = srcA + (size_t)(b * 1568 + (pos - 1) * 8 + t) * CC;
    } else {
        row = srcA + (size_t)r * CC;
    }
    int tid = threadIdx.x, lane = tid & 63, wave = tid >> 6;
    float x[3], s = 0.f, ss = 0.f;
#pragma unroll
    for (int i = 0; i < 3; i++) {
        float v = row[tid + i * 256];
        x[i] = v; s += v; ss += v * v;
    }
#pragma unroll
    for (int off = 32; off >= 1; off >>= 1) {
        s  += __shfl_xor(s, off);
        ss += __shfl_xor(ss, off);
    }
    __shared__ float red[2][4];
    if (lane == 0) { red[0][wave] = s; red[1][wave] = ss; }
    __syncthreads();
    float S   = red[0][0] + red[0][1] + red[0][2] + red[0][3];
    float SSQ = red[1][0] + red[1][1] + red[1][2] + red[1][3];
    float mean = S * (1.f / 768.f);
    float var = SSQ * (1.f / 768.f) - mean * mean;
    float inv = rsqrtf(var + 1e-6f);
#pragma unroll
    for (int i = 0; i < 3; i++) {
        int c = tid + i * 256;
        out[(size_t)r * CC + c] = f2bf((x[i] - mean) * inv * gamma[c] + beta[c]);
    }
}

// ---------------- MFMA GEMM (3-buffer prefetch, counted vmcnt) ----------------
// out[M][N] = A[M][K](bf16) @ BT[N][K]^T(bf16) + bias(f32)
// LDS element (row,k) at byte ((row*64 + (k/8)*16) ^ ((row&7)<<4)) + (k%8)*2, staged via
// global_load_lds with inverse-swizzled per-lane global source (linear LDS dest).
// Pipeline: tiles staged 2 ahead; s_waitcnt vmcnt(4) leaves the newest 4 loads in flight
// across the raw s_barrier (no compiler vmcnt(0) drain).
// mode 0: bf16 out = acc+bias
// mode 1: f32  out = acc+bias + resf[hidden skip-cls row]   (t_dense -> TEMB)
// mode 2: bf16 out = gelu(acc+bias)                          (fc1)
// mode 3: f32  out = acc+bias + resf[row*768+col]            (fc2 -> d_out, resf=HS)
__global__ __launch_bounds__(256) void k_gemm(
    const bf16* __restrict__ A, const bf16* __restrict__ BT,
    const float* __restrict__ bias, bf16* __restrict__ outb, float* __restrict__ outf,
    int M, int N, int K, int mode, const float* __restrict__ resf)
{
    __shared__ __align__(16) bf16 Asm[3][128 * 32];
    __shared__ __align__(16) bf16 Bsm[3][128 * 32];
    int tid = threadIdx.x, lane = tid & 63, wave = tid >> 6;
    int m0 = blockIdx.y * 128, n0 = blockIdx.x * 128;
    int wr = (wave >> 1) * 64, wc = (wave & 1) * 64;
    fx4 acc[4][4];
#pragma unroll
    for (int i = 0; i < 4; i++)
#pragma unroll
        for (int j = 0; j < 4; j++)
            acc[i][j] = fx4{0.f, 0.f, 0.f, 0.f};

    // inverse swizzle: lane l stages global (row rp, k-block gp) so the linear
    // LDS write at slot l lands where the swizzled read expects it.
    int s0 = lane & 1, s1 = (lane >> 1) & 1, s2 = (lane >> 2) & 1;
    int s3 = (lane >> 3) & 1, s4 = (lane >> 4) & 1, s5 = (lane >> 5) & 1;
    int rp = (s2 ^ s4) | (s3 << 1) | (s4 << 2) | (s5 << 3);
    int gp = (s0 ^ s2 ^ s4) | ((s1 ^ s3) << 1);

    const bf16* aG = A  + (size_t)(m0 + wave * 32 + rp) * K + gp * 8;
    const bf16* bG = BT + (size_t)(n0 + wave * 32 + rp) * K + gp * 8;
    int wo = wave * 32 * 32;   // wave's element offset in a tile buffer
    int c = lane & 15, gr = lane >> 4;
    int nt = K >> 5, ktLast = nt - 1;

    auto stage = [&](bf16* Ab, bf16* Bb, int kt) {
        const bf16* a = aG + kt * 32;
        const bf16* b = bG + kt * 32;
        gload16(a,          Ab + wo);
        gload16(a + 16 * K, Ab + wo + 16 * 32);
        gload16(b,          Bb + wo);
        gload16(b + 16 * K, Bb + wo + 16 * 32);
    };

    auto step = [&](const bf16* Ab, const bf16* Bb, bf16* An, bf16* Bn, int t) {
        asm volatile("s_waitcnt vmcnt(4)" ::: "memory");   // tile t ready; 4 newer loads stay in flight
        __builtin_amdgcn_s_barrier();
        __builtin_amdgcn_sched_barrier(0);
        int kt = t + 2; if (kt > ktLast) kt = ktLast;      // clamped tail keeps vmcnt uniform
        stage(An, Bn, kt);
        const char* Abt = (const char*)Ab;
        const char* Bbt = (const char*)Bb;
        bh8 af[4], bfr[4];
#pragma unroll
        for (int i = 0; i < 4; i++) {
            int ra = wr + i * 16 + c;
            af[i]  = *(const bh8*)(Abt + ((ra * 64 + gr * 16) ^ ((ra & 7) << 4)));
            int rb = wc + i * 16 + c;
            bfr[i] = *(const bh8*)(Bbt + ((rb * 64 + gr * 16) ^ ((rb & 7) << 4)));
        }
#pragma unroll
        for (int mi = 0; mi < 4; mi++)
#pragma unroll
            for (int ni = 0; ni < 4; ni++)
                acc[mi][ni] = __builtin_amdgcn_mfma_f32_16x16x32_bf16(af[mi], bfr[ni], acc[mi][ni], 0, 0, 0);
    };

    stage(Asm[0], Bsm[0], 0);
    stage(Asm[1], Bsm[1], 1);
    for (int t = 0; t < nt; t += 3) {   // nt is 24 or 96: divisible by 3
        step(Asm[0], Bsm[0], Asm[2], Bsm[2], t);
        step(Asm[1], Bsm[1], Asm[0], Bsm[0], t + 1);
        step(Asm[2], Bsm[2], Asm[1], Bsm[1], t + 2);
    }

#pragma unroll
    for (int mi = 0; mi < 4; mi++) {
#pragma unroll
        for (int ni = 0; ni < 4; ni++) {
            int col = n0 + wc + ni * 16 + (lane & 15);
            float bv = bias[col];
#pragma unroll
            for (int j = 0; j < 4; j++) {
                int row = m0 + wr + mi * 16 + (lane >> 4) * 4 + j;
                if (row < M) {
                    float v = acc[mi][ni][j] + bv;
                    if (mode == 2) {
                        v = 0.5f * v * (1.f + erff(v * 0.70710678118f));
                        outb[(size_t)row * N + col] = f2bf(v);
                    } else if (mode == 1) {
                        int b = row / 1568, rl = row - b * 1568;
                        v += resf[(size_t)(b * SS + 1 + rl) * CC + col];
                        outf[(size_t)row * N + col] = v;
                    } else if (mode == 3) {
                        v += resf[(size_t)row * CC + col];
                        outf[(size_t)row * N + col] = v;
                    } else {
                        outb[(size_t)row * N + col] = f2bf(v);
                    }
                }
            }
        }
    }
}

// ---------------- temporal attention: 1568 seqs, len 8, 12 heads ----------------
__global__ __launch_bounds__(256) void k_temporal_attn(
    const bf16* __restrict__ qkv,   // R_T x 2304
    bf16* __restrict__ ctx)         // R_T x 768
{
    int seq = blockIdx.x;
    int tid = threadIdx.x, lane = tid & 63, wave = tid >> 6;
    __shared__ float psm[4][8][8];
    const size_t base = (size_t)seq * 8 * 2304;
    for (int h = wave; h < 12; h += 4) {
        int qi = lane >> 3, kj = lane & 7;
        const bf16* qrow = qkv + base + (size_t)qi * 2304 + h * 64;
        const bf16* krow = qkv + base + (size_t)kj * 2304 + 768 + h * 64;
        float sc = 0.f;
#pragma unroll
        for (int d = 0; d < 64; d++) sc += bf2f(qrow[d]) * bf2f(krow[d]);
        sc *= 0.125f;
        float mx = sc;
#pragma unroll
        for (int off = 1; off < 8; off <<= 1) mx = fmaxf(mx, __shfl_xor(mx, off));
        float p = expf(sc - mx);
        float sum = p;
#pragma unroll
        for (int off = 1; off < 8; off <<= 1) sum += __shfl_xor(sum, off);
        p /= sum;
        psm[wave][qi][kj] = p;
        __syncthreads();
        int dq = lane >> 3, dbase = lane & 7;
        float pv[8];
#pragma unroll
        for (int k2 = 0; k2 < 8; k2++) pv[k2] = psm[wave][dq][k2];
#pragma unroll
        for (int jj = 0; jj < 8; jj++) {
            int d = dbase + 8 * jj;
            float a = 0.f;
#pragma unroll
            for (int k2 = 0; k2 < 8; k2++)
                a += pv[k2] * bf2f(qkv[base + (size_t)k2 * 2304 + 1536 + h * 64 + d]);
            ctx[((size_t)seq * 8 + dq) * CC + h * 64 + d] = f2bf(a);
        }
        __syncthreads();
    }
}

// ---------------- spatial attention (MFMA): one block per (seq, head) ----------------
#define SA_K_BYTES  25216
#define SA_VT_BYTES 28672
#define SA_P_BYTES  7168
__global__ __launch_bounds__(256) void k_spatial_attn(
    const bf16* __restrict__ qkv,   // R_S x 2304
    bf16* __restrict__ ctx)         // R_S x 768
{
    __shared__ __align__(16) char smem[SA_K_BYTES + SA_VT_BYTES + 4 * SA_P_BYTES];
    int head = blockIdx.x;   // 0..11
    int seq  = blockIdx.y;   // 0..63
    int tid = threadIdx.x, lane = tid & 63, wave = tid >> 6;
    const size_t base = (size_t)seq * 197 * 2304;
    char* Kb  = smem;
    char* VTb = smem + SA_K_BYTES;
    char* Pb  = smem + SA_K_BYTES + SA_VT_BYTES + wave * SA_P_BYTES;

    for (int idx = tid; idx < 197 * 8; idx += 256) {
        int row = idx >> 3, d8 = idx & 7;
        ivec4 v = *(const ivec4*)(qkv + base + (size_t)row * 2304 + 768 + head * 64 + d8 * 8);
        int byte = row * 128 + d8 * 16;
        *(ivec4*)(Kb + (byte ^ ((row & 7) << 4))) = v;
    }
    for (int e = tid; e < 64 * 224; e += 256) {
        int d = e & 63, r = e >> 6;
        bf16 v = (r < 197) ? qkv[base + (size_t)r * 2304 + 1536 + head * 64 + d] : f2bf(0.f);
        int byte = d * 448 + r * 2;
        *(bf16*)(VTb + (byte ^ ((d & 7) << 4))) = v;
    }
    for (int idx = lane; idx < 256; idx += 64) {
        int row = idx >> 4, col = 208 + (idx & 15);
        int byte = row * 448 + col * 2;
        *(bf16*)(Pb + (byte ^ ((row & 7) << 4))) = f2bf(0.f);
    }
    __syncthreads();

    int c = lane & 15, g = lane >> 4;
    for (int qt = wave; qt < 13; qt += 4) {
        int qrow = qt * 16 + c;
        int qr = qrow < 197 ? qrow : 196;
        const bf16* qp = qkv + base + (size_t)qr * 2304 + head * 64 + g * 8;
        bh8 qf0 = *(const bh8*)qp;
        bh8 qf1 = *(const bh8*)(qp + 32);

        fx4 s[13];
#pragma unroll
        for (int nt = 0; nt < 13; nt++) s[nt] = fx4{0.f, 0.f, 0.f, 0.f};
#pragma unroll
        for (int nt = 0; nt < 13; nt++) {
            int n = nt * 16 + c;
            int kbyte = n * 128 + g * 16;
            int swz = (n & 7) << 4;
            bh8 b0 = *(const bh8*)(Kb + ((kbyte) ^ swz));
            bh8 b1 = *(const bh8*)(Kb + ((kbyte + 64) ^ swz));
            s[nt] = __builtin_amdgcn_mfma_f32_16x16x32_bf16(qf0, b0, s[nt], 0, 0, 0);
            s[nt] = __builtin_amdgcn_mfma_f32_16x16x32_bf16(qf1, b1, s[nt], 0, 0, 0);
        }
#pragma unroll
        for (int nt = 0; nt < 13; nt++)
#pragma unroll
            for (int j = 0; j < 4; j++) s[nt][j] *= 0.125f;
        if (c >= 5) {
#pragma unroll
            for (int j = 0; j < 4; j++) s[12][j] = -1e30f;
        }
#pragma unroll
        for (int j = 0; j < 4; j++) {
            float mx = s[0][j];
#pragma unroll
            for (int nt = 1; nt < 13; nt++) mx = fmaxf(mx, s[nt][j]);
#pragma unroll
            for (int off = 1; off < 16; off <<= 1) mx = fmaxf(mx, __shfl_xor(mx, off));
            float sum = 0.f;
#pragma unroll
            for (int nt = 0; nt < 13; nt++) {
                float p = __expf(s[nt][j] - mx);
                s[nt][j] = p; sum += p;
            }
#pragma unroll
            for (int off = 1; off < 16; off <<= 1) sum += __shfl_xor(sum, off);
            float inv = 1.f / sum;
#pragma unroll
            for (int nt = 0; nt < 13; nt++) s[nt][j] *= inv;
        }
#pragma unroll
        for (int nt = 0; nt < 13; nt++)
#pragma unroll
            for (int j = 0; j < 4; j++) {
                int row = g * 4 + j, col = nt * 16 + c;
                int byte = row * 448 + col * 2;
                *(bf16*)(Pb + (byte ^ ((row & 7) << 4))) = f2bf(s[nt][j]);
            }
        fx4 o[4];
#pragma unroll
        for (int dt = 0; dt < 4; dt++) o[dt] = fx4{0.f, 0.f, 0.f, 0.f};
#pragma unroll
        for (int kk = 0; kk < 7; kk++) {
            int abyte = c * 448 + kk * 64 + g * 16;
            bh8 pa = *(const bh8*)(Pb + (abyte ^ ((c & 7) << 4)));
#pragma unroll
            for (int dt = 0; dt < 4; dt++) {
                int d = dt * 16 + c;
                int vbyte = d * 448 + kk * 64 + g * 16;
                bh8 vb = *(const bh8*)(VTb + (vbyte ^ ((d & 7) << 4)));
                o[dt] = __builtin_amdgcn_mfma_f32_16x16x32_bf16(pa, vb, o[dt], 0, 0, 0);
            }
        }
#pragma unroll
        for (int j = 0; j < 4; j++) {
            int qrow_o = qt * 16 + g * 4 + j;
            if (qrow_o < 197) {
                bf16* op = ctx + ((size_t)(seq * 197 + qrow_o)) * CC + head * 64 + c;
#pragma unroll
                for (int dt = 0; dt < 4; dt++) op[dt * 16] = f2bf(o[dt][j]);
            }
        }
    }
}

// ---------------- hs assembly: hs = concat(cls,temb) + concat(cls_out,res_s) (fp32) ----------------
__global__ __launch_bounds__(256) void k_assemble(
    const float* __restrict__ hidden,  // B x 1569 x 768 (fp32)
    const float* __restrict__ temb,    // R_T x 768 (fp32)
    const bf16*  __restrict__ sout,    // R_S x 768 (bf16, spatial proj out)
    float* __restrict__ hs)            // R_H x 768 (fp32)
{
    int idx = blockIdx.x * 256 + threadIdx.x;
    if (idx >= R_H * CC) return;
    int c = idx % CC; int r = idx / CC;
    int b = r / SS, s = r - b * SS;
    float v;
    if (s == 0) {
        float m = 0.f;
#pragma unroll
        for (int t = 0; t < 8; t++)
            m += bf2f(sout[((size_t)(b * 8 + t) * 197) * CC + c]);
        v = hidden[(size_t)r * CC + c] + m * 0.125f;
    } else {
        int sl = s - 1; int hw = sl >> 3, t = sl & 7;
        v = temb[((size_t)b * 1568 + sl) * CC + c]
          + bf2f(sout[(((size_t)(b * 8 + t)) * 197 + 1 + hw) * CC + c]);
    }
    hs[idx] = v;
}

extern "C" void kernel_launch(void* const* d_in, const int* in_sizes, int n_in,
                              void* d_out, int out_size, void* d_ws, size_t ws_size,
                              hipStream_t stream)
{
    (void)in_sizes; (void)n_in; (void)out_size; (void)ws_size;
    const float* hidden    = (const float*)d_in[0];
    const float* ln_t_g    = (const float*)d_in[1];
    const float* ln_t_b    = (const float*)d_in[2];
    const float* t_qkv_w   = (const float*)d_in[3];
    const float* t_qkv_b   = (const float*)d_in[4];
    const float* t_proj_w  = (const float*)d_in[5];
    const float* t_proj_b  = (const float*)d_in[6];
    const float* t_dense_w = (const float*)d_in[7];
    const float* t_dense_b = (const float*)d_in[8];
    const float* ln1_g     = (const float*)d_in[9];
    const float* ln1_b     = (const float*)d_in[10];
    const float* s_qkv_w   = (const float*)d_in[11];
    const float* s_qkv_b   = (const float*)d_in[12];
    const float* s_proj_w  = (const float*)d_in[13];
    const float* s_proj_b  = (const float*)d_in[14];
    const float* ln2_g     = (const float*)d_in[15];
    const float* ln2_b     = (const float*)d_in[16];
    const float* fc1_w     = (const float*)d_in[17];
    const float* fc1_b     = (const float*)d_in[18];
    const float* fc2_w     = (const float*)d_in[19];
    const float* fc2_b     = (const float*)d_in[20];

    char* ws = (char*)d_ws;
    size_t off = 0;
    auto alloc = [&](size_t bytes) -> char* {
        char* p = ws + off; off += (bytes + 255) & ~(size_t)255; return p;
    };
    bf16* wt_tqkv   = (bf16*)alloc((size_t)2304 * 768 * 2);
    bf16* wt_tproj  = (bf16*)alloc((size_t)768 * 768 * 2);
    bf16* wt_tdense = (bf16*)alloc((size_t)768 * 768 * 2);
    bf16* wt_sqkv   = (bf16*)alloc((size_t)2304 * 768 * 2);
    bf16* wt_sproj  = (bf16*)alloc((size_t)768 * 768 * 2);
    bf16* wt_fc1    = (bf16*)alloc((size_t)3072 * 768 * 2);
    bf16* wt_fc2    = (bf16*)alloc((size_t)768 * 3072 * 2);
    bf16* X         = (bf16*)alloc((size_t)R_S * CC * 2);
    char* qkv_base  = alloc((size_t)R_S * 2304 * 2);   // QKV (later: MID overlaps QKV+CTX)
    bf16* CTX       = (bf16*)alloc((size_t)R_S * CC * 2);
    bf16* P         = (bf16*)alloc((size_t)R_S * CC * 2);
    float* TEMB     = (float*)alloc((size_t)R_T * CC * 4);
    float* HS       = (float*)alloc((size_t)R_H * CC * 4);
    bf16* QKV = (bf16*)qkv_base;
    bf16* MID = (bf16*)qkv_base;   // 77.12MB fits in QKV+CTX (77.46MB); P stays live for assemble

    dim3 blk(256);

    // weight transposes W[K][N] -> WT[N][K], fp32 -> bf16
    k_transpose<<<dim3(2304 / 32, 768 / 32), blk, 0, stream>>>(t_qkv_w, wt_tqkv, 768, 2304);
    k_transpose<<<dim3(768 / 32, 768 / 32), blk, 0, stream>>>(t_proj_w, wt_tproj, 768, 768);
    k_transpose<<<dim3(768 / 32, 768 / 32), blk, 0, stream>>>(t_dense_w, wt_tdense, 768, 768);
    k_transpose<<<dim3(2304 / 32, 768 / 32), blk, 0, stream>>>(s_qkv_w, wt_sqkv, 768, 2304);
    k_transpose<<<dim3(768 / 32, 768 / 32), blk, 0, stream>>>(s_proj_w, wt_sproj, 768, 768);
    k_transpose<<<dim3(3072 / 32, 768 / 32), blk, 0, stream>>>(fc1_w, wt_fc1, 768, 3072);
    k_transpose<<<dim3(768 / 32, 3072 / 32), blk, 0, stream>>>(fc2_w, wt_fc2, 3072, 768);

    // ---- temporal branch ----
    k_layernorm<<<R_T, blk, 0, stream>>>(nullptr, hidden, ln_t_g, ln_t_b, X, 0);
    k_gemm<<<dim3(18, 98), blk, 0, stream>>>(X, wt_tqkv, t_qkv_b, QKV, nullptr, R_T, 2304, 768, 0, nullptr);
    k_temporal_attn<<<1568, blk, 0, stream>>>(QKV, CTX);
    k_gemm<<<dim3(6, 98), blk, 0, stream>>>(CTX, wt_tproj, t_proj_b, P, nullptr, R_T, 768, 768, 0, nullptr);
    k_gemm<<<dim3(6, 98), blk, 0, stream>>>(P, wt_tdense, t_dense_b, nullptr, TEMB, R_T, 768, 768, 1, hidden);

    // ---- spatial branch ----
    k_layernorm<<<R_S, blk, 0, stream>>>(TEMB, hidden, ln1_g, ln1_b, X, 1);
    k_gemm<<<dim3(18, 99), blk, 0, stream>>>(X, wt_sqkv, s_qkv_b, QKV, nullptr, R_S, 2304, 768, 0, nullptr);
    k_spatial_attn<<<dim3(12, 64), blk, 0, stream>>>(QKV, CTX);
    k_gemm<<<dim3(6, 99), blk, 0, stream>>>(CTX, wt_sproj, s_proj_b, P, nullptr, R_S, 768, 768, 0, nullptr);

    // ---- assemble hs (fp32) ----
    k_assemble<<<(R_H * CC + 255) / 256, blk, 0, stream>>>(hidden, TEMB, P, HS);

    // ---- MLP ----
    k_layernorm<<<R_H, blk, 0, stream>>>(HS, nullptr, ln2_g, ln2_b, X, 2);
    k_gemm<<<dim3(24, 99), blk, 0, stream>>>(X, wt_fc1, fc1_b, MID, nullptr, R_H, 3072, 768, 2, nullptr);
    k_gemm<<<dim3(6, 99), blk, 0, stream>>>(MID, wt_fc2, fc2_b, nullptr, (float*)d_out, R_H, 768, 3072, 3, HS);
}

// Round 6
// 832.541 us; speedup vs baseline: 1.0343x; 1.0343x over previous
//
#include <hip/hip_runtime.h>
#include <hip/hip_bf16.h>

typedef short bh8 __attribute__((ext_vector_type(8)));
typedef float fx4 __attribute__((ext_vector_type(4)));
typedef int ivec4 __attribute__((ext_vector_type(4)));

typedef __hip_bfloat16 bf16;

__device__ __forceinline__ float bf2f(bf16 v) { return __bfloat162float(v); }
__device__ __forceinline__ bf16 f2bf(float v) { return __float2bfloat16(v); }

// Problem constants
#define BB 8
#define SS 1569
#define CC 768
#define TT 8
#define HWN 196
#define R_T 12544   // B*HW*T
#define R_S 12608   // B*T*197
#define R_H 12552   // B*S

// async global->LDS, 16B per lane; lds dest is wave-uniform base + lane*16
__device__ __forceinline__ void gload16(const void* g, void* l) {
    __builtin_amdgcn_global_load_lds(
        (const __attribute__((address_space(1))) void*)g,
        (__attribute__((address_space(3))) void*)l, 16, 0, 0);
}

// swizzled LDS fragment read: element (row, slot) of a [*][64]bf16 tile (128B rows),
// byte = (row*128 + slot*16) ^ ((row&7)<<4)
__device__ __forceinline__ bh8 ldsw(const bf16* base, int row, int slot) {
    const char* p = (const char*)base;
    int byte = (row * 128 + slot * 16) ^ ((row & 7) << 4);
    return *(const bh8*)(p + byte);
}

// ---------------- transpose + fp32->bf16: out[C][R] = (bf16)in[R][C] ----------------
__global__ __launch_bounds__(256) void k_transpose(const float* __restrict__ in,
                                                   bf16* __restrict__ out,
                                                   int R, int C)
{
    __shared__ float sm[32][33];
    int c0 = blockIdx.x * 32, r0 = blockIdx.y * 32;
    int t = threadIdx.x;
#pragma unroll
    for (int i = 0; i < 4; i++) {
        int e = t + i * 256;
        int r = e >> 5, c = e & 31;
        sm[r][c] = in[(size_t)(r0 + r) * C + (c0 + c)];
    }
    __syncthreads();
#pragma unroll
    for (int i = 0; i < 4; i++) {
        int e = t + i * 256;
        int r = e >> 5, c = e & 31;
        out[(size_t)(c0 + r) * R + (r0 + c)] = f2bf(sm[c][r]);
    }
}

// ---------------- LayerNorm over C=768, one block per row; fp32 in -> bf16 out ----------------
__global__ __launch_bounds__(256) void k_layernorm(
    const float* __restrict__ srcA, const float* __restrict__ srcB,
    const float* __restrict__ gamma, const float* __restrict__ beta,
    bf16* __restrict__ out, int mode)
{
    int r = blockIdx.x;
    const float* row;
    if (mode == 0) {
        int b = r / 1568, rl = r - b * 1568;
        row = srcB + (size_t)(b * SS + 1 + rl) * CC;
    } else if (mode == 1) {
        int seq = r / 197, pos = r - seq * 197;
        int b = seq >> 3, t = seq & 7;
        if (pos == 0) row = srcB + (size_t)(b * SS) * CC;
        else          row = srcA + (size_t)(b * 1568 + (pos - 1) * 8 + t) * CC;
    } else {
        row = srcA + (size_t)r * CC;
    }
    int tid = threadIdx.x, lane = tid & 63, wave = tid >> 6;
    float x[3], s = 0.f, ss = 0.f;
#pragma unroll
    for (int i = 0; i < 3; i++) {
        float v = row[tid + i * 256];
        x[i] = v; s += v; ss += v * v;
    }
#pragma unroll
    for (int off = 32; off >= 1; off >>= 1) {
        s  += __shfl_xor(s, off);
        ss += __shfl_xor(ss, off);
    }
    __shared__ float red[2][4];
    if (lane == 0) { red[0][wave] = s; red[1][wave] = ss; }
    __syncthreads();
    float S   = red[0][0] + red[0][1] + red[0][2] + red[0][3];
    float SSQ = red[1][0] + red[1][1] + red[1][2] + red[1][3];
    float mean = S * (1.f / 768.f);
    float var = SSQ * (1.f / 768.f) - mean * mean;
    float inv = rsqrtf(var + 1e-6f);
#pragma unroll
    for (int i = 0; i < 3; i++) {
        int c = tid + i * 256;
        out[(size_t)r * CC + c] = f2bf((x[i] - mean) * inv * gamma[c] + beta[c]);
    }
}

// ---------------- 256x256 8-phase MFMA GEMM (T2+T3+T4+T5) ----------------
// out[M][N] = A[M][K](bf16) @ BT[N][K]^T(bf16) + bias; gelu!=0 -> exact GELU.
// 512 threads = 8 waves (2M x 4N), each owns 128x64 of C. BK=64, LDS 128KB (2 dbuf).
// Staging: global_load_lds, linear LDS dest, inverse-swizzled per-lane global source;
// reads use byte ^= (row&7)<<4. Full next tile staged at phase 0; vmcnt(0) only at
// phase 3 (3 phases of latency cover). N must be a multiple of 256; M-tail guarded
// (OOB A-tile rows read adjacent ws garbage, results discarded by row<M).
__global__ __launch_bounds__(512) void k_gemm256(
    const bf16* __restrict__ A, const bf16* __restrict__ BT,
    const float* __restrict__ bias, bf16* __restrict__ outb,
    int M, int N, int K, int gelu)
{
    __shared__ __align__(16) bf16 LA[2][256 * 64];
    __shared__ __align__(16) bf16 LB[2][256 * 64];
    int tid = threadIdx.x, lane = tid & 63, wave = tid >> 6;
    int m0 = blockIdx.y * 256, n0 = blockIdx.x * 256;
    int wr = (wave >> 2) * 128, wc = (wave & 3) * 64;
    int c = lane & 15, gr = lane >> 4;

    fx4 acc[8][4];
#pragma unroll
    for (int i = 0; i < 8; i++)
#pragma unroll
        for (int j = 0; j < 4; j++) acc[i][j] = fx4{0.f, 0.f, 0.f, 0.f};

    // staging source: lane l covers row (l>>3), k-block (l&7)^(l>>3) of its wave's 8-row slab
    int rlo = lane >> 3;
    int kblk = (lane & 7) ^ rlo;
    const bf16* aSrc = A  + (size_t)(m0 + wave * 8 + rlo) * K + kblk * 8;
    const bf16* bSrc = BT + (size_t)(n0 + wave * 8 + rlo) * K + kblk * 8;
    int wOff = wave * 8 * 64;   // wave's element offset within a 64-row line group
    int nt = K >> 6;

    auto stage = [&](bf16* nA, bf16* nB, int t) {
        const bf16* a = aSrc + (size_t)t * 64;
        const bf16* b = bSrc + (size_t)t * 64;
#pragma unroll
        for (int j = 0; j < 4; j++) {
            gload16(a + (size_t)j * 64 * K, nA + wOff + j * 64 * 64);
            gload16(b + (size_t)j * 64 * K, nB + wOff + j * 64 * 64);
        }
    };

    auto tile = [&](int t, const bf16* cA, const bf16* cB, bf16* nA, bf16* nB) {
        bh8 afr[4][2], bfr0[2][2], bfr1[2][2];
        // ---- phase 0: read A(m0-3)+B(n0-1); stage tile t+1; MFMA Q0
#pragma unroll
        for (int i = 0; i < 4; i++)
#pragma unroll
            for (int kk = 0; kk < 2; kk++)
                afr[i][kk] = ldsw(cA, wr + i * 16 + c, kk * 4 + gr);
#pragma unroll
        for (int nf = 0; nf < 2; nf++)
#pragma unroll
            for (int kk = 0; kk < 2; kk++)
                bfr0[nf][kk] = ldsw(cB, wc + nf * 16 + c, kk * 4 + gr);
        if (t + 1 < nt) stage(nA, nB, t + 1);
        __builtin_amdgcn_s_barrier();
        __builtin_amdgcn_s_setprio(1);
#pragma unroll
        for (int i = 0; i < 4; i++)
#pragma unroll
            for (int nf = 0; nf < 2; nf++)
#pragma unroll
                for (int kk = 0; kk < 2; kk++)
                    acc[i][nf] = __builtin_amdgcn_mfma_f32_16x16x32_bf16(afr[i][kk], bfr0[nf][kk], acc[i][nf], 0, 0, 0);
        __builtin_amdgcn_s_setprio(0);
        __builtin_amdgcn_s_barrier();
        // ---- phase 1: read B(n2-3); MFMA Q1 (A(m0-3) x B(n2-3))
#pragma unroll
        for (int nf = 0; nf < 2; nf++)
#pragma unroll
            for (int kk = 0; kk < 2; kk++)
                bfr1[nf][kk] = ldsw(cB, wc + 32 + nf * 16 + c, kk * 4 + gr);
        __builtin_amdgcn_s_barrier();
        __builtin_amdgcn_s_setprio(1);
#pragma unroll
        for (int i = 0; i < 4; i++)
#pragma unroll
            for (int nf = 0; nf < 2; nf++)
#pragma unroll
                for (int kk = 0; kk < 2; kk++)
                    acc[i][2 + nf] = __builtin_amdgcn_mfma_f32_16x16x32_bf16(afr[i][kk], bfr1[nf][kk], acc[i][2 + nf], 0, 0, 0);
        __builtin_amdgcn_s_setprio(0);
        __builtin_amdgcn_s_barrier();
        // ---- phase 2: read A(m4-7) (reuse afr); MFMA Q2 (A(m4-7) x B(n0-1))
#pragma unroll
        for (int i = 0; i < 4; i++)
#pragma unroll
            for (int kk = 0; kk < 2; kk++)
                afr[i][kk] = ldsw(cA, wr + 64 + i * 16 + c, kk * 4 + gr);
        __builtin_amdgcn_s_barrier();
        __builtin_amdgcn_s_setprio(1);
#pragma unroll
        for (int i = 0; i < 4; i++)
#pragma unroll
            for (int nf = 0; nf < 2; nf++)
#pragma unroll
                for (int kk = 0; kk < 2; kk++)
                    acc[4 + i][nf] = __builtin_amdgcn_mfma_f32_16x16x32_bf16(afr[i][kk], bfr0[nf][kk], acc[4 + i][nf], 0, 0, 0);
        __builtin_amdgcn_s_setprio(0);
        __builtin_amdgcn_s_barrier();
        // ---- phase 3: MFMA Q3 (A(m4-7) x B(n2-3)); drain stage before buffer swap
        __builtin_amdgcn_s_barrier();
        __builtin_amdgcn_s_setprio(1);
#pragma unroll
        for (int i = 0; i < 4; i++)
#pragma unroll
            for (int nf = 0; nf < 2; nf++)
#pragma unroll
                for (int kk = 0; kk < 2; kk++)
                    acc[4 + i][2 + nf] = __builtin_amdgcn_mfma_f32_16x16x32_bf16(afr[i][kk], bfr1[nf][kk], acc[4 + i][2 + nf], 0, 0, 0);
        __builtin_amdgcn_s_setprio(0);
        asm volatile("s_waitcnt vmcnt(0)" ::: "memory");
        __builtin_amdgcn_s_barrier();
    };

    stage(&LA[0][0], &LB[0][0], 0);
    asm volatile("s_waitcnt vmcnt(0)" ::: "memory");
    __builtin_amdgcn_s_barrier();
#pragma unroll 1
    for (int t2 = 0; t2 < nt; t2 += 2) {   // nt = 12: even
        tile(t2,     &LA[0][0], &LB[0][0], &LA[1][0], &LB[1][0]);
        tile(t2 + 1, &LA[1][0], &LB[1][0], &LA[0][0], &LB[0][0]);
    }

#pragma unroll
    for (int i = 0; i < 8; i++) {
#pragma unroll
        for (int nf = 0; nf < 4; nf++) {
            int col = n0 + wc + nf * 16 + c;
            float bv = bias[col];
#pragma unroll
            for (int j = 0; j < 4; j++) {
                int row = m0 + wr + i * 16 + gr * 4 + j;
                if (row < M) {
                    float v = acc[i][nf][j] + bv;
                    if (gelu) v = 0.5f * v * (1.f + erff(v * 0.70710678118f));
                    outb[(size_t)row * N + col] = f2bf(v);
                }
            }
        }
    }
}

// ---------------- 128x128 MFMA GEMM (m97 structure) for N=768 / fc2 GEMMs ----------------
// mode 0: bf16 out = acc+bias
// mode 1: f32  out = acc+bias + resf[hidden skip-cls row]   (t_dense -> TEMB)
// mode 3: f32  out = acc+bias + resf[row*768+col]            (fc2 -> d_out, resf=HS)
__global__ __launch_bounds__(256) void k_gemm(
    const bf16* __restrict__ A, const bf16* __restrict__ BT,
    const float* __restrict__ bias, bf16* __restrict__ outb, float* __restrict__ outf,
    int M, int N, int K, int mode, const float* __restrict__ resf)
{
    __shared__ __align__(16) bf16 Asm[128 * 32];
    __shared__ __align__(16) bf16 Bsm[128 * 32];
    int tid = threadIdx.x, lane = tid & 63, wave = tid >> 6;
    int m0 = blockIdx.y * 128, n0 = blockIdx.x * 128;
    int wr = (wave >> 1) * 64, wc = (wave & 1) * 64;
    fx4 acc[4][4];
#pragma unroll
    for (int i = 0; i < 4; i++)
#pragma unroll
        for (int j = 0; j < 4; j++)
            acc[i][j] = fx4{0.f, 0.f, 0.f, 0.f};

    int s0 = lane & 1, s1 = (lane >> 1) & 1, s2 = (lane >> 2) & 1;
    int s3 = (lane >> 3) & 1, s4 = (lane >> 4) & 1, s5 = (lane >> 5) & 1;
    int rp = (s2 ^ s4) | (s3 << 1) | (s4 << 2) | (s5 << 3);
    int gp = (s0 ^ s2 ^ s4) | ((s1 ^ s3) << 1);

    const bf16* aG = A  + (size_t)(m0 + wave * 32 + rp) * K + gp * 8;
    const bf16* bG = BT + (size_t)(n0 + wave * 32 + rp) * K + gp * 8;
    bf16* aL0 = Asm + (wave * 32) * 32;
    bf16* aL1 = Asm + (wave * 32 + 16) * 32;
    bf16* bL0 = Bsm + (wave * 32) * 32;
    bf16* bL1 = Bsm + (wave * 32 + 16) * 32;

    const char* Ab = (const char*)Asm;
    const char* Bb = (const char*)Bsm;
    int c = lane & 15, gr = lane >> 4;

    for (int k0 = 0; k0 < K; k0 += 32) {
        __syncthreads();
        gload16(aG, aL0);
        gload16(aG + 16 * K, aL1);
        gload16(bG, bL0);
        gload16(bG + 16 * K, bL1);
        aG += 32; bG += 32;
        __syncthreads();
        bh8 af[4], bfr[4];
#pragma unroll
        for (int i = 0; i < 4; i++) {
            int ra = wr + i * 16 + c;
            af[i]  = *(const bh8*)(Ab + ((ra * 64 + gr * 16) ^ ((ra & 7) << 4)));
            int rb = wc + i * 16 + c;
            bfr[i] = *(const bh8*)(Bb + ((rb * 64 + gr * 16) ^ ((rb & 7) << 4)));
        }
#pragma unroll
        for (int mi = 0; mi < 4; mi++)
#pragma unroll
            for (int ni = 0; ni < 4; ni++)
                acc[mi][ni] = __builtin_amdgcn_mfma_f32_16x16x32_bf16(af[mi], bfr[ni], acc[mi][ni], 0, 0, 0);
    }

#pragma unroll
    for (int mi = 0; mi < 4; mi++) {
#pragma unroll
        for (int ni = 0; ni < 4; ni++) {
            int col = n0 + wc + ni * 16 + (lane & 15);
            float bv = bias[col];
#pragma unroll
            for (int j = 0; j < 4; j++) {
                int row = m0 + wr + mi * 16 + (lane >> 4) * 4 + j;
                if (row < M) {
                    float v = acc[mi][ni][j] + bv;
                    if (mode == 1) {
                        int b = row / 1568, rl = row - b * 1568;
                        v += resf[(size_t)(b * SS + 1 + rl) * CC + col];
                        outf[(size_t)row * N + col] = v;
                    } else if (mode == 3) {
                        v += resf[(size_t)row * CC + col];
                        outf[(size_t)row * N + col] = v;
                    } else {
                        outb[(size_t)row * N + col] = f2bf(v);
                    }
                }
            }
        }
    }
}

// ---------------- temporal attention: 1568 seqs, len 8, 12 heads ----------------
__global__ __launch_bounds__(256) void k_temporal_attn(
    const bf16* __restrict__ qkv,   // R_T x 2304
    bf16* __restrict__ ctx)         // R_T x 768
{
    int seq = blockIdx.x;
    int tid = threadIdx.x, lane = tid & 63, wave = tid >> 6;
    __shared__ float psm[4][8][8];
    const size_t base = (size_t)seq * 8 * 2304;
    for (int h = wave; h < 12; h += 4) {
        int qi = lane >> 3, kj = lane & 7;
        const bf16* qrow = qkv + base + (size_t)qi * 2304 + h * 64;
        const bf16* krow = qkv + base + (size_t)kj * 2304 + 768 + h * 64;
        float sc = 0.f;
#pragma unroll
        for (int d = 0; d < 64; d++) sc += bf2f(qrow[d]) * bf2f(krow[d]);
        sc *= 0.125f;
        float mx = sc;
#pragma unroll
        for (int off = 1; off < 8; off <<= 1) mx = fmaxf(mx, __shfl_xor(mx, off));
        float p = expf(sc - mx);
        float sum = p;
#pragma unroll
        for (int off = 1; off < 8; off <<= 1) sum += __shfl_xor(sum, off);
        p /= sum;
        psm[wave][qi][kj] = p;
        __syncthreads();
        int dq = lane >> 3, dbase = lane & 7;
        float pv[8];
#pragma unroll
        for (int k2 = 0; k2 < 8; k2++) pv[k2] = psm[wave][dq][k2];
#pragma unroll
        for (int jj = 0; jj < 8; jj++) {
            int d = dbase + 8 * jj;
            float a = 0.f;
#pragma unroll
            for (int k2 = 0; k2 < 8; k2++)
                a += pv[k2] * bf2f(qkv[base + (size_t)k2 * 2304 + 1536 + h * 64 + d]);
            ctx[((size_t)seq * 8 + dq) * CC + h * 64 + d] = f2bf(a);
        }
        __syncthreads();
    }
}

// ---------------- spatial attention (MFMA): one block per (seq, head) ----------------
#define SA_K_BYTES  25216
#define SA_VT_BYTES 28672
#define SA_P_BYTES  7168
__global__ __launch_bounds__(256) void k_spatial_attn(
    const bf16* __restrict__ qkv,   // R_S x 2304
    bf16* __restrict__ ctx)         // R_S x 768
{
    __shared__ __align__(16) char smem[SA_K_BYTES + SA_VT_BYTES + 4 * SA_P_BYTES];
    int head = blockIdx.x;   // 0..11
    int seq  = blockIdx.y;   // 0..63
    int tid = threadIdx.x, lane = tid & 63, wave = tid >> 6;
    const size_t base = (size_t)seq * 197 * 2304;
    char* Kb  = smem;
    char* VTb = smem + SA_K_BYTES;
    char* Pb  = smem + SA_K_BYTES + SA_VT_BYTES + wave * SA_P_BYTES;

    for (int idx = tid; idx < 197 * 8; idx += 256) {
        int row = idx >> 3, d8 = idx & 7;
        ivec4 v = *(const ivec4*)(qkv + base + (size_t)row * 2304 + 768 + head * 64 + d8 * 8);
        int byte = row * 128 + d8 * 16;
        *(ivec4*)(Kb + (byte ^ ((row & 7) << 4))) = v;
    }
    for (int e = tid; e < 64 * 224; e += 256) {
        int d = e & 63, r = e >> 6;
        bf16 v = (r < 197) ? qkv[base + (size_t)r * 2304 + 1536 + head * 64 + d] : f2bf(0.f);
        int byte = d * 448 + r * 2;
        *(bf16*)(VTb + (byte ^ ((d & 7) << 4))) = v;
    }
    for (int idx = lane; idx < 256; idx += 64) {
        int row = idx >> 4, col = 208 + (idx & 15);
        int byte = row * 448 + col * 2;
        *(bf16*)(Pb + (byte ^ ((row & 7) << 4))) = f2bf(0.f);
    }
    __syncthreads();

    int c = lane & 15, g = lane >> 4;
    for (int qt = wave; qt < 13; qt += 4) {
        int qrow = qt * 16 + c;
        int qr = qrow < 197 ? qrow : 196;
        const bf16* qp = qkv + base + (size_t)qr * 2304 + head * 64 + g * 8;
        bh8 qf0 = *(const bh8*)qp;
        bh8 qf1 = *(const bh8*)(qp + 32);

        fx4 s[13];
#pragma unroll
        for (int nt = 0; nt < 13; nt++) s[nt] = fx4{0.f, 0.f, 0.f, 0.f};
#pragma unroll
        for (int nt = 0; nt < 13; nt++) {
            int n = nt * 16 + c;
            int kbyte = n * 128 + g * 16;
            int swz = (n & 7) << 4;
            bh8 b0 = *(const bh8*)(Kb + ((kbyte) ^ swz));
            bh8 b1 = *(const bh8*)(Kb + ((kbyte + 64) ^ swz));
            s[nt] = __builtin_amdgcn_mfma_f32_16x16x32_bf16(qf0, b0, s[nt], 0, 0, 0);
            s[nt] = __builtin_amdgcn_mfma_f32_16x16x32_bf16(qf1, b1, s[nt], 0, 0, 0);
        }
#pragma unroll
        for (int nt = 0; nt < 13; nt++)
#pragma unroll
            for (int j = 0; j < 4; j++) s[nt][j] *= 0.125f;
        if (c >= 5) {
#pragma unroll
            for (int j = 0; j < 4; j++) s[12][j] = -1e30f;
        }
#pragma unroll
        for (int j = 0; j < 4; j++) {
            float mx = s[0][j];
#pragma unroll
            for (int nt = 1; nt < 13; nt++) mx = fmaxf(mx, s[nt][j]);
#pragma unroll
            for (int off = 1; off < 16; off <<= 1) mx = fmaxf(mx, __shfl_xor(mx, off));
            float sum = 0.f;
#pragma unroll
            for (int nt = 0; nt < 13; nt++) {
                float p = __expf(s[nt][j] - mx);
                s[nt][j] = p; sum += p;
            }
#pragma unroll
            for (int off = 1; off < 16; off <<= 1) sum += __shfl_xor(sum, off);
            float inv = 1.f / sum;
#pragma unroll
            for (int nt = 0; nt < 13; nt++) s[nt][j] *= inv;
        }
#pragma unroll
        for (int nt = 0; nt < 13; nt++)
#pragma unroll
            for (int j = 0; j < 4; j++) {
                int row = g * 4 + j, col = nt * 16 + c;
                int byte = row * 448 + col * 2;
                *(bf16*)(Pb + (byte ^ ((row & 7) << 4))) = f2bf(s[nt][j]);
            }
        fx4 o[4];
#pragma unroll
        for (int dt = 0; dt < 4; dt++) o[dt] = fx4{0.f, 0.f, 0.f, 0.f};
#pragma unroll
        for (int kk = 0; kk < 7; kk++) {
            int abyte = c * 448 + kk * 64 + g * 16;
            bh8 pa = *(const bh8*)(Pb + (abyte ^ ((c & 7) << 4)));
#pragma unroll
            for (int dt = 0; dt < 4; dt++) {
                int d = dt * 16 + c;
                int vbyte = d * 448 + kk * 64 + g * 16;
                bh8 vb = *(const bh8*)(VTb + (vbyte ^ ((d & 7) << 4)));
                o[dt] = __builtin_amdgcn_mfma_f32_16x16x32_bf16(pa, vb, o[dt], 0, 0, 0);
            }
        }
#pragma unroll
        for (int j = 0; j < 4; j++) {
            int qrow_o = qt * 16 + g * 4 + j;
            if (qrow_o < 197) {
                bf16* op = ctx + ((size_t)(seq * 197 + qrow_o)) * CC + head * 64 + c;
#pragma unroll
                for (int dt = 0; dt < 4; dt++) op[dt * 16] = f2bf(o[dt][j]);
            }
        }
    }
}

// ---------------- hs assembly: hs = concat(cls,temb) + concat(cls_out,res_s) (fp32) ----------------
__global__ __launch_bounds__(256) void k_assemble(
    const float* __restrict__ hidden,  // B x 1569 x 768 (fp32)
    const float* __restrict__ temb,    // R_T x 768 (fp32)
    const bf16*  __restrict__ sout,    // R_S x 768 (bf16, spatial proj out)
    float* __restrict__ hs)            // R_H x 768 (fp32)
{
    int idx = blockIdx.x * 256 + threadIdx.x;
    if (idx >= R_H * CC) return;
    int c = idx % CC; int r = idx / CC;
    int b = r / SS, s = r - b * SS;
    float v;
    if (s == 0) {
        float m = 0.f;
#pragma unroll
        for (int t = 0; t < 8; t++)
            m += bf2f(sout[((size_t)(b * 8 + t) * 197) * CC + c]);
        v = hidden[(size_t)r * CC + c] + m * 0.125f;
    } else {
        int sl = s - 1; int hw = sl >> 3, t = sl & 7;
        v = temb[((size_t)b * 1568 + sl) * CC + c]
          + bf2f(sout[(((size_t)(b * 8 + t)) * 197 + 1 + hw) * CC + c]);
    }
    hs[idx] = v;
}

extern "C" void kernel_launch(void* const* d_in, const int* in_sizes, int n_in,
                              void* d_out, int out_size, void* d_ws, size_t ws_size,
                              hipStream_t stream)
{
    (void)in_sizes; (void)n_in; (void)out_size; (void)ws_size;
    const float* hidden    = (const float*)d_in[0];
    const float* ln_t_g    = (const float*)d_in[1];
    const float* ln_t_b    = (const float*)d_in[2];
    const float* t_qkv_w   = (const float*)d_in[3];
    const float* t_qkv_b   = (const float*)d_in[4];
    const float* t_proj_w  = (const float*)d_in[5];
    const float* t_proj_b  = (const float*)d_in[6];
    const float* t_dense_w = (const float*)d_in[7];
    const float* t_dense_b = (const float*)d_in[8];
    const float* ln1_g     = (const float*)d_in[9];
    const float* ln1_b     = (const float*)d_in[10];
    const float* s_qkv_w   = (const float*)d_in[11];
    const float* s_qkv_b   = (const float*)d_in[12];
    const float* s_proj_w  = (const float*)d_in[13];
    const float* s_proj_b  = (const float*)d_in[14];
    const float* ln2_g     = (const float*)d_in[15];
    const float* ln2_b     = (const float*)d_in[16];
    const float* fc1_w     = (const float*)d_in[17];
    const float* fc1_b     = (const float*)d_in[18];
    const float* fc2_w     = (const float*)d_in[19];
    const float* fc2_b     = (const float*)d_in[20];

    char* ws = (char*)d_ws;
    size_t off = 0;
    auto alloc = [&](size_t bytes) -> char* {
        char* p = ws + off; off += (bytes + 255) & ~(size_t)255; return p;
    };
    bf16* wt_tqkv   = (bf16*)alloc((size_t)2304 * 768 * 2);
    bf16* wt_tproj  = (bf16*)alloc((size_t)768 * 768 * 2);
    bf16* wt_tdense = (bf16*)alloc((size_t)768 * 768 * 2);
    bf16* wt_sqkv   = (bf16*)alloc((size_t)2304 * 768 * 2);
    bf16* wt_sproj  = (bf16*)alloc((size_t)768 * 768 * 2);
    bf16* wt_fc1    = (bf16*)alloc((size_t)3072 * 768 * 2);
    bf16* wt_fc2    = (bf16*)alloc((size_t)768 * 3072 * 2);
    bf16* X         = (bf16*)alloc((size_t)R_S * CC * 2);
    char* qkv_base  = alloc((size_t)R_S * 2304 * 2);   // QKV (later: MID overlaps QKV+CTX)
    bf16* CTX       = (bf16*)alloc((size_t)R_S * CC * 2);
    bf16* P         = (bf16*)alloc((size_t)R_S * CC * 2);
    float* TEMB     = (float*)alloc((size_t)R_T * CC * 4);
    float* HS       = (float*)alloc((size_t)R_H * CC * 4);
    bf16* QKV = (bf16*)qkv_base;
    bf16* MID = (bf16*)qkv_base;   // 77.12MB fits in QKV+CTX (77.46MB); P stays live for assemble

    dim3 blk(256);
    dim3 blk512(512);

    // weight transposes W[K][N] -> WT[N][K], fp32 -> bf16
    k_transpose<<<dim3(2304 / 32, 768 / 32), blk, 0, stream>>>(t_qkv_w, wt_tqkv, 768, 2304);
    k_transpose<<<dim3(768 / 32, 768 / 32), blk, 0, stream>>>(t_proj_w, wt_tproj, 768, 768);
    k_transpose<<<dim3(768 / 32, 768 / 32), blk, 0, stream>>>(t_dense_w, wt_tdense, 768, 768);
    k_transpose<<<dim3(2304 / 32, 768 / 32), blk, 0, stream>>>(s_qkv_w, wt_sqkv, 768, 2304);
    k_transpose<<<dim3(768 / 32, 768 / 32), blk, 0, stream>>>(s_proj_w, wt_sproj, 768, 768);
    k_transpose<<<dim3(3072 / 32, 768 / 32), blk, 0, stream>>>(fc1_w, wt_fc1, 768, 3072);
    k_transpose<<<dim3(768 / 32, 3072 / 32), blk, 0, stream>>>(fc2_w, wt_fc2, 3072, 768);

    // ---- temporal branch ----
    k_layernorm<<<R_T, blk, 0, stream>>>(nullptr, hidden, ln_t_g, ln_t_b, X, 0);
    k_gemm256<<<dim3(9, 49), blk512, 0, stream>>>(X, wt_tqkv, t_qkv_b, QKV, R_T, 2304, 768, 0);
    k_temporal_attn<<<1568, blk, 0, stream>>>(QKV, CTX);
    k_gemm<<<dim3(6, 98), blk, 0, stream>>>(CTX, wt_tproj, t_proj_b, P, nullptr, R_T, 768, 768, 0, nullptr);
    k_gemm<<<dim3(6, 98), blk, 0, stream>>>(P, wt_tdense, t_dense_b, nullptr, TEMB, R_T, 768, 768, 1, hidden);

    // ---- spatial branch ----
    k_layernorm<<<R_S, blk, 0, stream>>>(TEMB, hidden, ln1_g, ln1_b, X, 1);
    k_gemm256<<<dim3(9, 50), blk512, 0, stream>>>(X, wt_sqkv, s_qkv_b, QKV, R_S, 2304, 768, 0);
    k_spatial_attn<<<dim3(12, 64), blk, 0, stream>>>(QKV, CTX);
    k_gemm<<<dim3(6, 99), blk, 0, stream>>>(CTX, wt_sproj, s_proj_b, P, nullptr, R_S, 768, 768, 0, nullptr);

    // ---- assemble hs (fp32) ----
    k_assemble<<<(R_H * CC + 255) / 256, blk, 0, stream>>>(hidden, TEMB, P, HS);

    // ---- MLP ----
    k_layernorm<<<R_H, blk, 0, stream>>>(HS, nullptr, ln2_g, ln2_b, X, 2);
    k_gemm256<<<dim3(12, 50), blk512, 0, stream>>>(X, wt_fc1, fc1_b, MID, R_H, 3072, 768, 1);
    k_gemm<<<dim3(6, 99), blk, 0, stream>>>(MID, wt_fc2, fc2_b, nullptr, (float*)d_out, R_H, 768, 3072, 3, HS);
}

// Round 7
// 791.690 us; speedup vs baseline: 1.0876x; 1.0516x over previous
//
#include <hip/hip_runtime.h>
#include <hip/hip_bf16.h>

typedef short bh8 __attribute__((ext_vector_type(8)));
typedef float fx4 __attribute__((ext_vector_type(4)));
typedef int ivec4 __attribute__((ext_vector_type(4)));

typedef __hip_bfloat16 bf16;

__device__ __forceinline__ float bf2f(bf16 v) { return __bfloat162float(v); }
__device__ __forceinline__ bf16 f2bf(float v) { return __float2bfloat16(v); }

// Problem constants
#define BB 8
#define SS 1569
#define CC 768
#define TT 8
#define HWN 196
#define R_T 12544   // B*HW*T
#define R_S 12608   // B*T*197
#define R_H 12552   // B*S

// async global->LDS, 16B per lane; lds dest is wave-uniform base + lane*16
__device__ __forceinline__ void gload16(const void* g, void* l) {
    __builtin_amdgcn_global_load_lds(
        (const __attribute__((address_space(1))) void*)g,
        (__attribute__((address_space(3))) void*)l, 16, 0, 0);
}

// swizzled LDS fragment read: element (row, slot) of a [*][64]bf16 tile (128B rows)
__device__ __forceinline__ bh8 ldsw(const bf16* base, int row, int slot) {
    const char* p = (const char*)base;
    int byte = (row * 128 + slot * 16) ^ ((row & 7) << 4);
    return *(const bh8*)(p + byte);
}

// bijective XCD-chunked block swizzle (m204): hardware id o (round-robins XCDs)
// -> logical id such that each XCD owns a contiguous chunk of logical blocks.
__device__ __forceinline__ int xcd_swz(int o, int nwg) {
    int q = nwg >> 3, r = nwg & 7;
    int xcd = o & 7, idx = o >> 3;
    int base = (xcd < r) ? xcd * (q + 1) : r * (q + 1) + (xcd - r) * q;
    return base + idx;
}

// ---------------- transpose + fp32->bf16: out[C][R] = (bf16)in[R][C] ----------------
__global__ __launch_bounds__(256) void k_transpose(const float* __restrict__ in,
                                                   bf16* __restrict__ out,
                                                   int R, int C)
{
    __shared__ float sm[32][33];
    int c0 = blockIdx.x * 32, r0 = blockIdx.y * 32;
    int t = threadIdx.x;
#pragma unroll
    for (int i = 0; i < 4; i++) {
        int e = t + i * 256;
        int r = e >> 5, c = e & 31;
        sm[r][c] = in[(size_t)(r0 + r) * C + (c0 + c)];
    }
    __syncthreads();
#pragma unroll
    for (int i = 0; i < 4; i++) {
        int e = t + i * 256;
        int r = e >> 5, c = e & 31;
        out[(size_t)(c0 + r) * R + (r0 + c)] = f2bf(sm[c][r]);
    }
}

// ---------------- LayerNorm over C=768, one block per row; fp32 in -> bf16 out ----------------
__global__ __launch_bounds__(256) void k_layernorm(
    const float* __restrict__ srcA, const float* __restrict__ srcB,
    const float* __restrict__ gamma, const float* __restrict__ beta,
    bf16* __restrict__ out, int mode)
{
    int r = blockIdx.x;
    const float* row;
    if (mode == 0) {
        int b = r / 1568, rl = r - b * 1568;
        row = srcB + (size_t)(b * SS + 1 + rl) * CC;
    } else if (mode == 1) {
        int seq = r / 197, pos = r - seq * 197;
        int b = seq >> 3, t = seq & 7;
        if (pos == 0) row = srcB + (size_t)(b * SS) * CC;
        else          row = srcA + (size_t)(b * 1568 + (pos - 1) * 8 + t) * CC;
    } else {
        row = srcA + (size_t)r * CC;
    }
    int tid = threadIdx.x, lane = tid & 63, wave = tid >> 6;
    float x[3], s = 0.f, ss = 0.f;
#pragma unroll
    for (int i = 0; i < 3; i++) {
        float v = row[tid + i * 256];
        x[i] = v; s += v; ss += v * v;
    }
#pragma unroll
    for (int off = 32; off >= 1; off >>= 1) {
        s  += __shfl_xor(s, off);
        ss += __shfl_xor(ss, off);
    }
    __shared__ float red[2][4];
    if (lane == 0) { red[0][wave] = s; red[1][wave] = ss; }
    __syncthreads();
    float S   = red[0][0] + red[0][1] + red[0][2] + red[0][3];
    float SSQ = red[1][0] + red[1][1] + red[1][2] + red[1][3];
    float mean = S * (1.f / 768.f);
    float var = SSQ * (1.f / 768.f) - mean * mean;
    float inv = rsqrtf(var + 1e-6f);
#pragma unroll
    for (int i = 0; i < 3; i++) {
        int c = tid + i * 256;
        out[(size_t)r * CC + c] = f2bf((x[i] - mean) * inv * gamma[c] + beta[c]);
    }
}

// ---------------- 256x256 8-phase MFMA GEMM (T1+T2+T3+T4+T5) ----------------
// out[M][N] = A[M][K](bf16) @ BT[N][K]^T(bf16) + bias; gelu!=0 -> exact GELU.
__global__ __launch_bounds__(512) void k_gemm256(
    const bf16* __restrict__ A, const bf16* __restrict__ BT,
    const float* __restrict__ bias, bf16* __restrict__ outb,
    int M, int N, int K, int gelu)
{
    __shared__ __align__(16) bf16 LA[2][256 * 64];
    __shared__ __align__(16) bf16 LB[2][256 * 64];
    int tid = threadIdx.x, lane = tid & 63, wave = tid >> 6;
    int nbx = gridDim.x;
    int f = xcd_swz(blockIdx.y * nbx + blockIdx.x, nbx * gridDim.y);
    int m0 = (f / nbx) * 256, n0 = (f % nbx) * 256;
    int wr = (wave >> 2) * 128, wc = (wave & 3) * 64;
    int c = lane & 15, gr = lane >> 4;

    fx4 acc[8][4];
#pragma unroll
    for (int i = 0; i < 8; i++)
#pragma unroll
        for (int j = 0; j < 4; j++) acc[i][j] = fx4{0.f, 0.f, 0.f, 0.f};

    // staging source: lane l covers row (l>>3), k-block (l&7)^(l>>3) of its wave's 8-row slab
    int rlo = lane >> 3;
    int kblk = (lane & 7) ^ rlo;
    const bf16* aSrc = A  + (size_t)(m0 + wave * 8 + rlo) * K + kblk * 8;
    const bf16* bSrc = BT + (size_t)(n0 + wave * 8 + rlo) * K + kblk * 8;
    int wOff = wave * 8 * 64;
    int nt = K >> 6;

    auto stage = [&](bf16* nA, bf16* nB, int t) {
        const bf16* a = aSrc + (size_t)t * 64;
        const bf16* b = bSrc + (size_t)t * 64;
#pragma unroll
        for (int j = 0; j < 4; j++) {
            gload16(a + (size_t)j * 64 * K, nA + wOff + j * 64 * 64);
            gload16(b + (size_t)j * 64 * K, nB + wOff + j * 64 * 64);
        }
    };

    auto tile = [&](int t, const bf16* cA, const bf16* cB, bf16* nA, bf16* nB) {
        bh8 afr[4][2], bfr0[2][2], bfr1[2][2];
        // ---- phase 0: read A(m0-3)+B(n0-1); stage tile t+1; MFMA Q0
#pragma unroll
        for (int i = 0; i < 4; i++)
#pragma unroll
            for (int kk = 0; kk < 2; kk++)
                afr[i][kk] = ldsw(cA, wr + i * 16 + c, kk * 4 + gr);
#pragma unroll
        for (int nf = 0; nf < 2; nf++)
#pragma unroll
            for (int kk = 0; kk < 2; kk++)
                bfr0[nf][kk] = ldsw(cB, wc + nf * 16 + c, kk * 4 + gr);
        if (t + 1 < nt) stage(nA, nB, t + 1);
        __builtin_amdgcn_s_barrier();
        __builtin_amdgcn_s_setprio(1);
#pragma unroll
        for (int i = 0; i < 4; i++)
#pragma unroll
            for (int nf = 0; nf < 2; nf++)
#pragma unroll
                for (int kk = 0; kk < 2; kk++)
                    acc[i][nf] = __builtin_amdgcn_mfma_f32_16x16x32_bf16(afr[i][kk], bfr0[nf][kk], acc[i][nf], 0, 0, 0);
        __builtin_amdgcn_s_setprio(0);
        __builtin_amdgcn_s_barrier();
        // ---- phase 1: read B(n2-3); MFMA Q1
#pragma unroll
        for (int nf = 0; nf < 2; nf++)
#pragma unroll
            for (int kk = 0; kk < 2; kk++)
                bfr1[nf][kk] = ldsw(cB, wc + 32 + nf * 16 + c, kk * 4 + gr);
        __builtin_amdgcn_s_barrier();
        __builtin_amdgcn_s_setprio(1);
#pragma unroll
        for (int i = 0; i < 4; i++)
#pragma unroll
            for (int nf = 0; nf < 2; nf++)
#pragma unroll
                for (int kk = 0; kk < 2; kk++)
                    acc[i][2 + nf] = __builtin_amdgcn_mfma_f32_16x16x32_bf16(afr[i][kk], bfr1[nf][kk], acc[i][2 + nf], 0, 0, 0);
        __builtin_amdgcn_s_setprio(0);
        __builtin_amdgcn_s_barrier();
        // ---- phase 2: read A(m4-7); MFMA Q2
#pragma unroll
        for (int i = 0; i < 4; i++)
#pragma unroll
            for (int kk = 0; kk < 2; kk++)
                afr[i][kk] = ldsw(cA, wr + 64 + i * 16 + c, kk * 4 + gr);
        __builtin_amdgcn_s_barrier();
        __builtin_amdgcn_s_setprio(1);
#pragma unroll
        for (int i = 0; i < 4; i++)
#pragma unroll
            for (int nf = 0; nf < 2; nf++)
#pragma unroll
                for (int kk = 0; kk < 2; kk++)
                    acc[4 + i][nf] = __builtin_amdgcn_mfma_f32_16x16x32_bf16(afr[i][kk], bfr0[nf][kk], acc[4 + i][nf], 0, 0, 0);
        __builtin_amdgcn_s_setprio(0);
        __builtin_amdgcn_s_barrier();
        // ---- phase 3: MFMA Q3; drain stage before buffer swap
        __builtin_amdgcn_s_barrier();
        __builtin_amdgcn_s_setprio(1);
#pragma unroll
        for (int i = 0; i < 4; i++)
#pragma unroll
            for (int nf = 0; nf < 2; nf++)
#pragma unroll
                for (int kk = 0; kk < 2; kk++)
                    acc[4 + i][2 + nf] = __builtin_amdgcn_mfma_f32_16x16x32_bf16(afr[i][kk], bfr1[nf][kk], acc[4 + i][2 + nf], 0, 0, 0);
        __builtin_amdgcn_s_setprio(0);
        asm volatile("s_waitcnt vmcnt(0)" ::: "memory");
        __builtin_amdgcn_s_barrier();
    };

    stage(&LA[0][0], &LB[0][0], 0);
    asm volatile("s_waitcnt vmcnt(0)" ::: "memory");
    __builtin_amdgcn_s_barrier();
#pragma unroll 1
    for (int t2 = 0; t2 < nt; t2 += 2) {
        tile(t2,     &LA[0][0], &LB[0][0], &LA[1][0], &LB[1][0]);
        tile(t2 + 1, &LA[1][0], &LB[1][0], &LA[0][0], &LB[0][0]);
    }

#pragma unroll
    for (int i = 0; i < 8; i++) {
#pragma unroll
        for (int nf = 0; nf < 4; nf++) {
            int col = n0 + wc + nf * 16 + c;
            float bv = bias[col];
#pragma unroll
            for (int j = 0; j < 4; j++) {
                int row = m0 + wr + i * 16 + gr * 4 + j;
                if (row < M) {
                    float v = acc[i][nf][j] + bv;
                    if (gelu) v = 0.5f * v * (1.f + erff(v * 0.70710678118f));
                    outb[(size_t)row * N + col] = f2bf(v);
                }
            }
        }
    }
}

// ---------------- 128x128 MFMA GEMM (m97 structure) for N=768 / fc2 GEMMs ----------------
// mode 0: bf16 out = acc+bias
// mode 1: f32  out = acc+bias + resf[hidden skip-cls row]   (t_dense -> TEMB)
// mode 3: f32  out = acc+bias + resf[row*768+col]            (fc2 -> d_out, resf=HS)
__global__ __launch_bounds__(256) void k_gemm(
    const bf16* __restrict__ A, const bf16* __restrict__ BT,
    const float* __restrict__ bias, bf16* __restrict__ outb, float* __restrict__ outf,
    int M, int N, int K, int mode, const float* __restrict__ resf)
{
    __shared__ __align__(16) bf16 Asm[128 * 32];
    __shared__ __align__(16) bf16 Bsm[128 * 32];
    int tid = threadIdx.x, lane = tid & 63, wave = tid >> 6;
    int nbx = gridDim.x;
    int f = xcd_swz(blockIdx.y * nbx + blockIdx.x, nbx * gridDim.y);
    int m0 = (f / nbx) * 128, n0 = (f % nbx) * 128;
    int wr = (wave >> 1) * 64, wc = (wave & 1) * 64;
    fx4 acc[4][4];
#pragma unroll
    for (int i = 0; i < 4; i++)
#pragma unroll
        for (int j = 0; j < 4; j++)
            acc[i][j] = fx4{0.f, 0.f, 0.f, 0.f};

    int s0 = lane & 1, s1 = (lane >> 1) & 1, s2 = (lane >> 2) & 1;
    int s3 = (lane >> 3) & 1, s4 = (lane >> 4) & 1, s5 = (lane >> 5) & 1;
    int rp = (s2 ^ s4) | (s3 << 1) | (s4 << 2) | (s5 << 3);
    int gp = (s0 ^ s2 ^ s4) | ((s1 ^ s3) << 1);

    const bf16* aG = A  + (size_t)(m0 + wave * 32 + rp) * K + gp * 8;
    const bf16* bG = BT + (size_t)(n0 + wave * 32 + rp) * K + gp * 8;
    bf16* aL0 = Asm + (wave * 32) * 32;
    bf16* aL1 = Asm + (wave * 32 + 16) * 32;
    bf16* bL0 = Bsm + (wave * 32) * 32;
    bf16* bL1 = Bsm + (wave * 32 + 16) * 32;

    const char* Ab = (const char*)Asm;
    const char* Bb = (const char*)Bsm;
    int c = lane & 15, gr = lane >> 4;

    for (int k0 = 0; k0 < K; k0 += 32) {
        __syncthreads();
        gload16(aG, aL0);
        gload16(aG + 16 * K, aL1);
        gload16(bG, bL0);
        gload16(bG + 16 * K, bL1);
        aG += 32; bG += 32;
        __syncthreads();
        bh8 af[4], bfr[4];
#pragma unroll
        for (int i = 0; i < 4; i++) {
            int ra = wr + i * 16 + c;
            af[i]  = *(const bh8*)(Ab + ((ra * 64 + gr * 16) ^ ((ra & 7) << 4)));
            int rb = wc + i * 16 + c;
            bfr[i] = *(const bh8*)(Bb + ((rb * 64 + gr * 16) ^ ((rb & 7) << 4)));
        }
#pragma unroll
        for (int mi = 0; mi < 4; mi++)
#pragma unroll
            for (int ni = 0; ni < 4; ni++)
                acc[mi][ni] = __builtin_amdgcn_mfma_f32_16x16x32_bf16(af[mi], bfr[ni], acc[mi][ni], 0, 0, 0);
    }

#pragma unroll
    for (int mi = 0; mi < 4; mi++) {
#pragma unroll
        for (int ni = 0; ni < 4; ni++) {
            int col = n0 + wc + ni * 16 + (lane & 15);
            float bv = bias[col];
#pragma unroll
            for (int j = 0; j < 4; j++) {
                int row = m0 + wr + mi * 16 + (lane >> 4) * 4 + j;
                if (row < M) {
                    float v = acc[mi][ni][j] + bv;
                    if (mode == 1) {
                        int b = row / 1568, rl = row - b * 1568;
                        v += resf[(size_t)(b * SS + 1 + rl) * CC + col];
                        outf[(size_t)row * N + col] = v;
                    } else if (mode == 3) {
                        v += resf[(size_t)row * CC + col];
                        outf[(size_t)row * N + col] = v;
                    } else {
                        outb[(size_t)row * N + col] = f2bf(v);
                    }
                }
            }
        }
    }
}

// ---------------- temporal attention: 1568 seqs, len 8, 12 heads ----------------
__global__ __launch_bounds__(256) void k_temporal_attn(
    const bf16* __restrict__ qkv,   // R_T x 2304
    bf16* __restrict__ ctx)         // R_T x 768
{
    int seq = blockIdx.x;
    int tid = threadIdx.x, lane = tid & 63, wave = tid >> 6;
    __shared__ float psm[4][8][8];
    const size_t base = (size_t)seq * 8 * 2304;
    for (int h = wave; h < 12; h += 4) {
        int qi = lane >> 3, kj = lane & 7;
        const bf16* qrow = qkv + base + (size_t)qi * 2304 + h * 64;
        const bf16* krow = qkv + base + (size_t)kj * 2304 + 768 + h * 64;
        float sc = 0.f;
#pragma unroll
        for (int d = 0; d < 64; d++) sc += bf2f(qrow[d]) * bf2f(krow[d]);
        sc *= 0.125f;
        float mx = sc;
#pragma unroll
        for (int off = 1; off < 8; off <<= 1) mx = fmaxf(mx, __shfl_xor(mx, off));
        float p = expf(sc - mx);
        float sum = p;
#pragma unroll
        for (int off = 1; off < 8; off <<= 1) sum += __shfl_xor(sum, off);
        p /= sum;
        psm[wave][qi][kj] = p;
        __syncthreads();
        int dq = lane >> 3, dbase = lane & 7;
        float pv[8];
#pragma unroll
        for (int k2 = 0; k2 < 8; k2++) pv[k2] = psm[wave][dq][k2];
#pragma unroll
        for (int jj = 0; jj < 8; jj++) {
            int d = dbase + 8 * jj;
            float a = 0.f;
#pragma unroll
            for (int k2 = 0; k2 < 8; k2++)
                a += pv[k2] * bf2f(qkv[base + (size_t)k2 * 2304 + 1536 + h * 64 + d]);
            ctx[((size_t)seq * 8 + dq) * CC + h * 64 + d] = f2bf(a);
        }
        __syncthreads();
    }
}

// ---------------- spatial attention (MFMA): one block per (seq, head) ----------------
#define SA_K_BYTES  25216
#define SA_VT_BYTES 28672
#define SA_P_BYTES  7168
__global__ __launch_bounds__(256) void k_spatial_attn(
    const bf16* __restrict__ qkv,   // R_S x 2304
    bf16* __restrict__ ctx)         // R_S x 768
{
    __shared__ __align__(16) char smem[SA_K_BYTES + SA_VT_BYTES + 4 * SA_P_BYTES];
    int head = blockIdx.x;   // 0..11
    int seq  = blockIdx.y;   // 0..63
    int tid = threadIdx.x, lane = tid & 63, wave = tid >> 6;
    const size_t base = (size_t)seq * 197 * 2304;
    char* Kb  = smem;
    char* VTb = smem + SA_K_BYTES;
    char* Pb  = smem + SA_K_BYTES + SA_VT_BYTES + wave * SA_P_BYTES;

    for (int idx = tid; idx < 197 * 8; idx += 256) {
        int row = idx >> 3, d8 = idx & 7;
        ivec4 v = *(const ivec4*)(qkv + base + (size_t)row * 2304 + 768 + head * 64 + d8 * 8);
        int byte = row * 128 + d8 * 16;
        *(ivec4*)(Kb + (byte ^ ((row & 7) << 4))) = v;
    }
    for (int e = tid; e < 64 * 224; e += 256) {
        int d = e & 63, r = e >> 6;
        bf16 v = (r < 197) ? qkv[base + (size_t)r * 2304 + 1536 + head * 64 + d] : f2bf(0.f);
        int byte = d * 448 + r * 2;
        *(bf16*)(VTb + (byte ^ ((d & 7) << 4))) = v;
    }
    for (int idx = lane; idx < 256; idx += 64) {
        int row = idx >> 4, col = 208 + (idx & 15);
        int byte = row * 448 + col * 2;
        *(bf16*)(Pb + (byte ^ ((row & 7) << 4))) = f2bf(0.f);
    }
    __syncthreads();

    int c = lane & 15, g = lane >> 4;
    for (int qt = wave; qt < 13; qt += 4) {
        int qrow = qt * 16 + c;
        int qr = qrow < 197 ? qrow : 196;
        const bf16* qp = qkv + base + (size_t)qr * 2304 + head * 64 + g * 8;
        bh8 qf0 = *(const bh8*)qp;
        bh8 qf1 = *(const bh8*)(qp + 32);

        fx4 s[13];
#pragma unroll
        for (int nt = 0; nt < 13; nt++) s[nt] = fx4{0.f, 0.f, 0.f, 0.f};
#pragma unroll
        for (int nt = 0; nt < 13; nt++) {
            int n = nt * 16 + c;
            int kbyte = n * 128 + g * 16;
            int swz = (n & 7) << 4;
            bh8 b0 = *(const bh8*)(Kb + ((kbyte) ^ swz));
            bh8 b1 = *(const bh8*)(Kb + ((kbyte + 64) ^ swz));
            s[nt] = __builtin_amdgcn_mfma_f32_16x16x32_bf16(qf0, b0, s[nt], 0, 0, 0);
            s[nt] = __builtin_amdgcn_mfma_f32_16x16x32_bf16(qf1, b1, s[nt], 0, 0, 0);
        }
#pragma unroll
        for (int nt = 0; nt < 13; nt++)
#pragma unroll
            for (int j = 0; j < 4; j++) s[nt][j] *= 0.125f;
        if (c >= 5) {
#pragma unroll
            for (int j = 0; j < 4; j++) s[12][j] = -1e30f;
        }
#pragma unroll
        for (int j = 0; j < 4; j++) {
            float mx = s[0][j];
#pragma unroll
            for (int nt = 1; nt < 13; nt++) mx = fmaxf(mx, s[nt][j]);
#pragma unroll
            for (int off = 1; off < 16; off <<= 1) mx = fmaxf(mx, __shfl_xor(mx, off));
            float sum = 0.f;
#pragma unroll
            for (int nt = 0; nt < 13; nt++) {
                float p = __expf(s[nt][j] - mx);
                s[nt][j] = p; sum += p;
            }
#pragma unroll
            for (int off = 1; off < 16; off <<= 1) sum += __shfl_xor(sum, off);
            float inv = 1.f / sum;
#pragma unroll
            for (int nt = 0; nt < 13; nt++) s[nt][j] *= inv;
        }
#pragma unroll
        for (int nt = 0; nt < 13; nt++)
#pragma unroll
            for (int j = 0; j < 4; j++) {
                int row = g * 4 + j, col = nt * 16 + c;
                int byte = row * 448 + col * 2;
                *(bf16*)(Pb + (byte ^ ((row & 7) << 4))) = f2bf(s[nt][j]);
            }
        fx4 o[4];
#pragma unroll
        for (int dt = 0; dt < 4; dt++) o[dt] = fx4{0.f, 0.f, 0.f, 0.f};
#pragma unroll
        for (int kk = 0; kk < 7; kk++) {
            int abyte = c * 448 + kk * 64 + g * 16;
            bh8 pa = *(const bh8*)(Pb + (abyte ^ ((c & 7) << 4)));
#pragma unroll
            for (int dt = 0; dt < 4; dt++) {
                int d = dt * 16 + c;
                int vbyte = d * 448 + kk * 64 + g * 16;
                bh8 vb = *(const bh8*)(VTb + (vbyte ^ ((d & 7) << 4)));
                o[dt] = __builtin_amdgcn_mfma_f32_16x16x32_bf16(pa, vb, o[dt], 0, 0, 0);
            }
        }
#pragma unroll
        for (int j = 0; j < 4; j++) {
            int qrow_o = qt * 16 + g * 4 + j;
            if (qrow_o < 197) {
                bf16* op = ctx + ((size_t)(seq * 197 + qrow_o)) * CC + head * 64 + c;
#pragma unroll
                for (int dt = 0; dt < 4; dt++) op[dt * 16] = f2bf(o[dt][j]);
            }
        }
    }
}

// ---------------- hs assembly: hs = concat(cls,temb) + concat(cls_out,res_s) (fp32) ----------------
__global__ __launch_bounds__(256) void k_assemble(
    const float* __restrict__ hidden,  // B x 1569 x 768 (fp32)
    const float* __restrict__ temb,    // R_T x 768 (fp32)
    const bf16*  __restrict__ sout,    // R_S x 768 (bf16, spatial proj out)
    float* __restrict__ hs)            // R_H x 768 (fp32)
{
    int idx = blockIdx.x * 256 + threadIdx.x;
    if (idx >= R_H * CC) return;
    int c = idx % CC; int r = idx / CC;
    int b = r / SS, s = r - b * SS;
    float v;
    if (s == 0) {
        float m = 0.f;
#pragma unroll
        for (int t = 0; t < 8; t++)
            m += bf2f(sout[((size_t)(b * 8 + t) * 197) * CC + c]);
        v = hidden[(size_t)r * CC + c] + m * 0.125f;
    } else {
        int sl = s - 1; int hw = sl >> 3, t = sl & 7;
        v = temb[((size_t)b * 1568 + sl) * CC + c]
          + bf2f(sout[(((size_t)(b * 8 + t)) * 197 + 1 + hw) * CC + c]);
    }
    hs[idx] = v;
}

extern "C" void kernel_launch(void* const* d_in, const int* in_sizes, int n_in,
                              void* d_out, int out_size, void* d_ws, size_t ws_size,
                              hipStream_t stream)
{
    (void)in_sizes; (void)n_in; (void)out_size; (void)ws_size;
    const float* hidden    = (const float*)d_in[0];
    const float* ln_t_g    = (const float*)d_in[1];
    const float* ln_t_b    = (const float*)d_in[2];
    const float* t_qkv_w   = (const float*)d_in[3];
    const float* t_qkv_b   = (const float*)d_in[4];
    const float* t_proj_w  = (const float*)d_in[5];
    const float* t_proj_b  = (const float*)d_in[6];
    const float* t_dense_w = (const float*)d_in[7];
    const float* t_dense_b = (const float*)d_in[8];
    const float* ln1_g     = (const float*)d_in[9];
    const float* ln1_b     = (const float*)d_in[10];
    const float* s_qkv_w   = (const float*)d_in[11];
    const float* s_qkv_b   = (const float*)d_in[12];
    const float* s_proj_w  = (const float*)d_in[13];
    const float* s_proj_b  = (const float*)d_in[14];
    const float* ln2_g     = (const float*)d_in[15];
    const float* ln2_b     = (const float*)d_in[16];
    const float* fc1_w     = (const float*)d_in[17];
    const float* fc1_b     = (const float*)d_in[18];
    const float* fc2_w     = (const float*)d_in[19];
    const float* fc2_b     = (const float*)d_in[20];

    char* ws = (char*)d_ws;
    size_t off = 0;
    auto alloc = [&](size_t bytes) -> char* {
        char* p = ws + off; off += (bytes + 255) & ~(size_t)255; return p;
    };
    bf16* wt_tqkv   = (bf16*)alloc((size_t)2304 * 768 * 2);
    bf16* wt_tproj  = (bf16*)alloc((size_t)768 * 768 * 2);
    bf16* wt_tdense = (bf16*)alloc((size_t)768 * 768 * 2);
    bf16* wt_sqkv   = (bf16*)alloc((size_t)2304 * 768 * 2);
    bf16* wt_sproj  = (bf16*)alloc((size_t)768 * 768 * 2);
    bf16* wt_fc1    = (bf16*)alloc((size_t)3072 * 768 * 2);
    bf16* wt_fc2    = (bf16*)alloc((size_t)768 * 3072 * 2);
    bf16* X         = (bf16*)alloc((size_t)R_S * CC * 2);
    char* qkv_base  = alloc((size_t)R_S * 2304 * 2);   // QKV (later: MID overlaps QKV+CTX)
    bf16* CTX       = (bf16*)alloc((size_t)R_S * CC * 2);
    bf16* P         = (bf16*)alloc((size_t)R_S * CC * 2);
    float* TEMB     = (float*)alloc((size_t)R_T * CC * 4);
    float* HS       = (float*)alloc((size_t)R_H * CC * 4);
    bf16* QKV = (bf16*)qkv_base;
    bf16* MID = (bf16*)qkv_base;   // 77.12MB fits in QKV+CTX (77.46MB); P stays live for assemble

    dim3 blk(256);
    dim3 blk512(512);

    // weight transposes W[K][N] -> WT[N][K], fp32 -> bf16
    k_transpose<<<dim3(2304 / 32, 768 / 32), blk, 0, stream>>>(t_qkv_w, wt_tqkv, 768, 2304);
    k_transpose<<<dim3(768 / 32, 768 / 32), blk, 0, stream>>>(t_proj_w, wt_tproj, 768, 768);
    k_transpose<<<dim3(768 / 32, 768 / 32), blk, 0, stream>>>(t_dense_w, wt_tdense, 768, 768);
    k_transpose<<<dim3(2304 / 32, 768 / 32), blk, 0, stream>>>(s_qkv_w, wt_sqkv, 768, 2304);
    k_transpose<<<dim3(768 / 32, 768 / 32), blk, 0, stream>>>(s_proj_w, wt_sproj, 768, 768);
    k_transpose<<<dim3(3072 / 32, 768 / 32), blk, 0, stream>>>(fc1_w, wt_fc1, 768, 3072);
    k_transpose<<<dim3(768 / 32, 3072 / 32), blk, 0, stream>>>(fc2_w, wt_fc2, 3072, 768);

    // ---- temporal branch ----
    k_layernorm<<<R_T, blk, 0, stream>>>(nullptr, hidden, ln_t_g, ln_t_b, X, 0);
    k_gemm256<<<dim3(9, 49), blk512, 0, stream>>>(X, wt_tqkv, t_qkv_b, QKV, R_T, 2304, 768, 0);
    k_temporal_attn<<<1568, blk, 0, stream>>>(QKV, CTX);
    k_gemm<<<dim3(6, 98), blk, 0, stream>>>(CTX, wt_tproj, t_proj_b, P, nullptr, R_T, 768, 768, 0, nullptr);
    k_gemm<<<dim3(6, 98), blk, 0, stream>>>(P, wt_tdense, t_dense_b, nullptr, TEMB, R_T, 768, 768, 1, hidden);

    // ---- spatial branch ----
    k_layernorm<<<R_S, blk, 0, stream>>>(TEMB, hidden, ln1_g, ln1_b, X, 1);
    k_gemm256<<<dim3(9, 50), blk512, 0, stream>>>(X, wt_sqkv, s_qkv_b, QKV, R_S, 2304, 768, 0);
    k_spatial_attn<<<dim3(12, 64), blk, 0, stream>>>(QKV, CTX);
    k_gemm<<<dim3(6, 99), blk, 0, stream>>>(CTX, wt_sproj, s_proj_b, P, nullptr, R_S, 768, 768, 0, nullptr);

    // ---- assemble hs (fp32) ----
    k_assemble<<<(R_H * CC + 255) / 256, blk, 0, stream>>>(hidden, TEMB, P, HS);

    // ---- MLP ----
    k_layernorm<<<R_H, blk, 0, stream>>>(HS, nullptr, ln2_g, ln2_b, X, 2);
    k_gemm256<<<dim3(12, 50), blk512, 0, stream>>>(X, wt_fc1, fc1_b, MID, R_H, 3072, 768, 1);
    k_gemm<<<dim3(6, 99), blk, 0, stream>>>(MID, wt_fc2, fc2_b, nullptr, (float*)d_out, R_H, 768, 3072, 3, HS);
}